// Round 9
// baseline (156.111 us; speedup 1.0000x reference)
//
#include <hip/hip_runtime.h>
#include <hip/hip_bf16.h>

#define Dx 300
#define Mx 1024

// float-offsets into ws
#define OFF_REP    0
#define OFF_DEP    307200
#define OFF_HEAD   614400
#define OFF_ATTN   921600

typedef __attribute__((ext_vector_type(8))) short short8;
typedef __attribute__((ext_vector_type(4))) float f32x4;

__device__ __forceinline__ float bf2f(unsigned short u) {
    union { unsigned int i; float f; } v; v.i = ((unsigned int)u) << 16; return v.f;
}
__device__ __forceinline__ unsigned short f2bf(float x) {   // RNE
    union { float f; unsigned int i; } u; u.f = x;
    unsigned int r = u.i + 0x7FFFu + ((u.i >> 16) & 1u);
    return (unsigned short)(r >> 16);
}
__device__ __forceinline__ void split2(float x, unsigned short* h, unsigned short* lo) {
    unsigned short hh = f2bf(x);
    *h = hh; *lo = f2bf(x - bf2f(hh));
}
__device__ __forceinline__ int detect_bf16(const void* w) {
    const unsigned short* u = (const unsigned short*)w;
    int ok = 1;
    #pragma unroll
    for (int t = 0; t < 64; ++t) { float v = bf2f(u[t]); ok &= (fabsf(v) < 1.0f) ? 1 : 0; }
    return ok;
}
__device__ __forceinline__ float ldf(const void* p, int idx, int isbf) {
    return isbf ? bf2f(((const unsigned short*)p)[idx]) : ((const float*)p)[idx];
}

// ---------------------------------------------------------------------------
// Shared MFMA tile shape: M=16 x N=64 per 256-thr block, K-chunks of 64.
// Wave w owns output subtile n in [n0+16w, n0+16w+16). hi/lo split: 3 MFMA.
// A-frag: A[m=l&15][k=(l>>4)*8+j]; C/D: n=l&15(col), m=(l>>4)*4+r(row).
// ---------------------------------------------------------------------------

// stage one B row-segment (16 k) from a weight row with bounds, hi/lo split
__device__ __forceinline__ void stageB_seg(
        const void* wrow, int valid_row, int k, int kmax, int isbf,
        unsigned short* Bh, unsigned short* Bl) {
    unsigned short h[16], lo[16];
    if (valid_row) {
        if (!isbf) {
            const float* Wp = (const float*)wrow;
            if (k + 16 <= kmax) {
                #pragma unroll
                for (int q = 0; q < 4; ++q) {
                    float4 wv = *(const float4*)(Wp + k + q * 4);
                    split2(wv.x, &h[q*4+0], &lo[q*4+0]);
                    split2(wv.y, &h[q*4+1], &lo[q*4+1]);
                    split2(wv.z, &h[q*4+2], &lo[q*4+2]);
                    split2(wv.w, &h[q*4+3], &lo[q*4+3]);
                }
            } else {
                #pragma unroll
                for (int j = 0; j < 16; ++j) {
                    float x = (k + j < kmax) ? Wp[k + j] : 0.f;
                    split2(x, &h[j], &lo[j]);
                }
            }
        } else {
            const unsigned short* Wp = (const unsigned short*)wrow;
            if (k + 16 <= kmax) {
                #pragma unroll
                for (int q = 0; q < 4; ++q) {
                    ushort4 wv = *(const ushort4*)(Wp + k + q * 4);
                    h[q*4+0] = wv.x; h[q*4+1] = wv.y; h[q*4+2] = wv.z; h[q*4+3] = wv.w;
                }
            } else {
                #pragma unroll
                for (int j = 0; j < 16; ++j) h[j] = (k + j < kmax) ? Wp[k + j] : 0;
            }
            #pragma unroll
            for (int j = 0; j < 16; ++j) lo[j] = 0;
        }
    } else {
        #pragma unroll
        for (int j = 0; j < 16; ++j) { h[j] = 0; lo[j] = 0; }
    }
    #pragma unroll
    for (int j = 0; j < 16; ++j) { Bh[j] = h[j]; Bl[j] = lo[j]; }
}

#define MM_COMPUTE()                                                           \
    _Pragma("unroll")                                                          \
    for (int ks = 0; ks < 2; ++ks) {                                           \
        const int kb = ks * 32 + (l >> 4) * 8;                                 \
        short8 a_h = *(const short8*)&Ah[l & 15][kb];                          \
        short8 a_l = *(const short8*)&Al[l & 15][kb];                          \
        short8 b_h = *(const short8*)&Bh[w * 16 + (l & 15)][kb];               \
        short8 b_l = *(const short8*)&Bl[w * 16 + (l & 15)][kb];               \
        acc = __builtin_amdgcn_mfma_f32_16x16x32_bf16(a_h, b_h, acc, 0, 0, 0); \
        acc = __builtin_amdgcn_mfma_f32_16x16x32_bf16(a_h, b_l, acc, 0, 0, 0); \
        acc = __builtin_amdgcn_mfma_f32_16x16x32_bf16(a_l, b_h, acc, 0, 0, 0); \
    }

// ---------------------------------------------------------------------------
// k_mm1: rep = elu(X @ Wfc^T + bfc). grid 320 = 64mt x 5nt.
// ---------------------------------------------------------------------------
__global__ __launch_bounds__(256) void k_mm1(
        const void* __restrict__ Xv, const void* __restrict__ Wfc,
        const void* __restrict__ bfc, float* __restrict__ ws) {
    __shared__ __align__(16) unsigned short Ah[16][72], Al[16][72];
    __shared__ __align__(16) unsigned short Bh[64][72], Bl[64][72];
    __shared__ int s_isbf;
    const int tid = threadIdx.x;
    if (tid == 0) s_isbf = detect_bf16(Wfc);
    __syncthreads();
    const int isbf = s_isbf;
    const int mt = blockIdx.x / 5, nt = blockIdx.x % 5;
    const int m0 = mt * 16, n0 = nt * 64;
    const int w = tid >> 6, l = tid & 63;
    const int arow = tid >> 4, akq = (tid & 15) * 4;
    const int brow = tid >> 2, bseg = (tid & 3) * 16;
    f32x4 acc = {0.f, 0.f, 0.f, 0.f};
    for (int kc = 0; kc < 5; ++kc) {
        const int k0 = kc * 64;
        __syncthreads();
        {   // A stage
            unsigned short h[4], lo[4];
            const int k = k0 + akq;
            if (isbf) {
                const unsigned short* Xp = (const unsigned short*)Xv + (m0 + arow) * 300;
                if (k < 300) {
                    ushort4 xv = *(const ushort4*)(Xp + k);
                    h[0] = xv.x; h[1] = xv.y; h[2] = xv.z; h[3] = xv.w;
                } else { h[0] = h[1] = h[2] = h[3] = 0; }
                lo[0] = lo[1] = lo[2] = lo[3] = 0;
            } else {
                const float* Xp = (const float*)Xv + (m0 + arow) * 300;
                if (k < 300) {
                    float4 xv = *(const float4*)(Xp + k);
                    split2(xv.x, &h[0], &lo[0]); split2(xv.y, &h[1], &lo[1]);
                    split2(xv.z, &h[2], &lo[2]); split2(xv.w, &h[3], &lo[3]);
                } else {
                    #pragma unroll
                    for (int j = 0; j < 4; ++j) { h[j] = 0; lo[j] = 0; }
                }
            }
            #pragma unroll
            for (int j = 0; j < 4; ++j) { Ah[arow][akq + j] = h[j]; Al[arow][akq + j] = lo[j]; }
        }
        {   // B stage
            const int n = n0 + brow;
            const void* wrow = isbf ? (const void*)((const unsigned short*)Wfc + n * 300)
                                    : (const void*)((const float*)Wfc + n * 300);
            stageB_seg(wrow, n < 300, k0 + bseg, 300, isbf,
                       &Bh[brow][bseg], &Bl[brow][bseg]);
        }
        __syncthreads();
        MM_COMPUTE()
    }
    const int n_g = n0 + w * 16 + (l & 15);
    if (n_g < 300) {
        float bb = ldf(bfc, n_g, isbf);
        #pragma unroll
        for (int r = 0; r < 4; ++r) {
            int m_g = m0 + (l >> 4) * 4 + r;
            float v = acc[r] + bb;
            v = v > 0.f ? v : (__expf(v) - 1.f);
            ws[OFF_REP + m_g * 300 + n_g] = v;
        }
    }
}

// ---------------------------------------------------------------------------
// k_mm2: dep = rep@W1^T + b1 ; head = rep@W2^T. grid 640 = 64mt x 10nt (Npad 640).
// ---------------------------------------------------------------------------
__global__ __launch_bounds__(256) void k_mm2(
        const void* __restrict__ W1, const void* __restrict__ W2,
        const void* __restrict__ b1, float* __restrict__ ws) {
    __shared__ __align__(16) unsigned short Ah[16][72], Al[16][72];
    __shared__ __align__(16) unsigned short Bh[64][72], Bl[64][72];
    __shared__ int s_isbf;
    const int tid = threadIdx.x;
    if (tid == 0) s_isbf = detect_bf16(W1);
    __syncthreads();
    const int isbf = s_isbf;
    const int mt = blockIdx.x / 10, nt = blockIdx.x % 10;
    const int m0 = mt * 16, n0 = nt * 64;
    const int w = tid >> 6, l = tid & 63;
    const int arow = tid >> 4, akq = (tid & 15) * 4;
    const int brow = tid >> 2, bseg = (tid & 3) * 16;
    f32x4 acc = {0.f, 0.f, 0.f, 0.f};
    for (int kc = 0; kc < 5; ++kc) {
        const int k0 = kc * 64;
        __syncthreads();
        {   // A stage from rep (fp32)
            unsigned short h[4], lo[4];
            const int k = k0 + akq;
            const float* Xp = ws + OFF_REP + (m0 + arow) * 300;
            if (k < 300) {
                float4 xv = *(const float4*)(Xp + k);
                split2(xv.x, &h[0], &lo[0]); split2(xv.y, &h[1], &lo[1]);
                split2(xv.z, &h[2], &lo[2]); split2(xv.w, &h[3], &lo[3]);
            } else {
                #pragma unroll
                for (int j = 0; j < 4; ++j) { h[j] = 0; lo[j] = 0; }
            }
            #pragma unroll
            for (int j = 0; j < 4; ++j) { Ah[arow][akq + j] = h[j]; Al[arow][akq + j] = lo[j]; }
        }
        {   // B stage: n<300 -> W1 row n; 320<=n<620 -> W2 row n-320
            const int n = n0 + brow;
            int vrow; const void* wrow;
            if (n < 300) {
                vrow = 1;
                wrow = isbf ? (const void*)((const unsigned short*)W1 + n * 300)
                            : (const void*)((const float*)W1 + n * 300);
            } else if (n >= 320 && n < 620) {
                vrow = 1;
                wrow = isbf ? (const void*)((const unsigned short*)W2 + (n - 320) * 300)
                            : (const void*)((const float*)W2 + (n - 320) * 300);
            } else { vrow = 0; wrow = W1; }
            stageB_seg(wrow, vrow, k0 + bseg, 300, isbf,
                       &Bh[brow][bseg], &Bl[brow][bseg]);
        }
        __syncthreads();
        MM_COMPUTE()
    }
    const int n_g = n0 + w * 16 + (l & 15);
    if (n_g < 300) {
        float bb = ldf(b1, n_g, isbf);
        #pragma unroll
        for (int r = 0; r < 4; ++r) {
            int m_g = m0 + (l >> 4) * 4 + r;
            ws[OFF_DEP + m_g * 300 + n_g] = acc[r] + bb;
        }
    } else if (n_g >= 320 && n_g < 620) {
        #pragma unroll
        for (int r = 0; r < 4; ++r) {
            int m_g = m0 + (l >> 4) * 4 + r;
            ws[OFF_HEAD + m_g * 300 + (n_g - 320)] = acc[r];
        }
    }
}

// ---------------------------------------------------------------------------
// k_attn: single-pass branchless, fixed shift m=C (round-4 proven).
// grid 512, 320 thr; 2-i tiles long/short interleaved.
// ---------------------------------------------------------------------------
__global__ __launch_bounds__(320) void k_attn(
        const float* __restrict__ ws_ro, const int* __restrict__ mask,
        float* __restrict__ attn) {
    const float* dep  = ws_ro + OFF_DEP;
    const float* head = ws_ro + OFF_HEAD;
    const float* rep  = ws_ro + OFF_REP;
    __shared__ float mkf[256];
    const int blk = blockIdx.x;
    const int b = blk >> 7;
    const int tile = blk & 127;
    const int u = tile >> 1;
    const int i0 = (tile & 1) ? (254 - 2 * u) : (2 * u);
    const int tid = threadIdx.x;
    if (tid < 256) mkf[tid] = (float)mask[b * 256 + tid];
    __syncthreads();
    const int d = tid;
    if (d >= Dx) return;
    const int base = b * 256;

    const float hv0 = head[(base + i0) * Dx + d];
    const float hv1 = head[(base + i0 + 1) * Dx + d];
    const float pw0 = __expf(0.4f * hv0);
    const float pw1 = __expf(0.4f * hv1);

    float s0 = 0.f, r0 = 0.f, s1 = 0.f, r1 = 0.f;
    {
        const int j = i0 + 1;
        float dv = dep[(base + j) * Dx + d];
        float rv = rep[(base + j) * Dx + d];
        float mk = mkf[j];
        float ex = __expf(0.4f * dv);
        float u0 = fmaf(ex, pw0, 1.0f);
        float e0 = __expf(-10.0f * __builtin_amdgcn_rcpf(u0));
        float em0 = e0 * mk;
        s0 += em0; r0 = fmaf(em0, rv, r0);
    }
    const float* dp = dep + base * Dx + d;
    const float* rp = rep + base * Dx + d;
    #pragma unroll 4
    for (int j = i0 + 2; j < 256; ++j) {
        float dv = dp[j * Dx];
        float rv = rp[j * Dx];
        float mk = mkf[j];
        float ex = __expf(0.4f * dv);
        float u0 = fmaf(ex, pw0, 1.0f);
        float u1 = fmaf(ex, pw1, 1.0f);
        float e0 = __expf(-10.0f * __builtin_amdgcn_rcpf(u0));
        float e1 = __expf(-10.0f * __builtin_amdgcn_rcpf(u1));
        float em0 = e0 * mk;
        float em1 = e1 * mk;
        s0 += em0; r0 = fmaf(em0, rv, r0);
        s1 += em1; r1 = fmaf(em1, rv, r1);
    }
    const float den0 = s0 + (s0 == 0.f ? 1.f : 0.f) + 1e-20f;
    const float den1 = s1 + (s1 == 0.f ? 1.f : 0.f) + 1e-20f;
    attn[(base + i0) * Dx + d]     = r0 / den0;
    attn[(base + i0 + 1) * Dx + d] = r1 / den1;
}

// ---------------------------------------------------------------------------
// k_mm3: gate GEMM over A=[rep|pad|attn|pad] (Kpad=640), B=[Wf1|Wf2] rows;
// sigmoid blend, mask, store. grid 320 = 64mt x 5nt.
// ---------------------------------------------------------------------------
__global__ __launch_bounds__(256) void k_mm3(
        const void* __restrict__ Wf1, const void* __restrict__ Wf2,
        const void* __restrict__ bfv, const int* __restrict__ mask,
        float* __restrict__ ws, void* __restrict__ outv) {
    __shared__ __align__(16) unsigned short Ah[16][72], Al[16][72];
    __shared__ __align__(16) unsigned short Bh[64][72], Bl[64][72];
    __shared__ int s_isbf;
    const int tid = threadIdx.x;
    if (tid == 0) s_isbf = detect_bf16(Wf1);
    __syncthreads();
    const int isbf = s_isbf;
    const int mt = blockIdx.x / 5, nt = blockIdx.x % 5;
    const int m0 = mt * 16, n0 = nt * 64;
    const int w = tid >> 6, l = tid & 63;
    const int arow = tid >> 4, akq = (tid & 15) * 4;
    const int brow = tid >> 2, bseg = (tid & 3) * 16;
    f32x4 acc = {0.f, 0.f, 0.f, 0.f};
    for (int kc = 0; kc < 10; ++kc) {
        const int k0 = kc * 64;
        __syncthreads();
        {   // A stage: k<300 rep; 320<=k<620 attn[k-320]; else 0 (all mult-4 regions)
            unsigned short h[4], lo[4];
            const int k = k0 + akq;
            const float* src = nullptr; int kk = k;
            if (k < 300) { src = ws + OFF_REP + (m0 + arow) * 300; }
            else if (k >= 320 && k < 620) { src = ws + OFF_ATTN + (m0 + arow) * 300; kk = k - 320; }
            if (src) {
                float4 xv = *(const float4*)(src + kk);
                split2(xv.x, &h[0], &lo[0]); split2(xv.y, &h[1], &lo[1]);
                split2(xv.z, &h[2], &lo[2]); split2(xv.w, &h[3], &lo[3]);
            } else {
                #pragma unroll
                for (int j = 0; j < 4; ++j) { h[j] = 0; lo[j] = 0; }
            }
            #pragma unroll
            for (int j = 0; j < 4; ++j) { Ah[arow][akq + j] = h[j]; Al[arow][akq + j] = lo[j]; }
        }
        {   // B stage: row n of [Wf1 k<300 | pad | Wf2 k-320 | pad], 16-seg may cross
            const int n = n0 + brow;
            const int k = k0 + bseg;
            unsigned short* bh = &Bh[brow][bseg];
            unsigned short* bl = &Bl[brow][bseg];
            if (n >= 300) {
                #pragma unroll
                for (int j = 0; j < 16; ++j) { bh[j] = 0; bl[j] = 0; }
            } else if (k + 16 <= 300) {
                const void* wrow = isbf ? (const void*)((const unsigned short*)Wf1 + n * 300)
                                        : (const void*)((const float*)Wf1 + n * 300);
                stageB_seg(wrow, 1, k, 300, isbf, bh, bl);
            } else if (k >= 320 && k + 16 <= 620) {
                const void* wrow = isbf ? (const void*)((const unsigned short*)Wf2 + n * 300)
                                        : (const void*)((const float*)Wf2 + n * 300);
                stageB_seg(wrow, 1, k - 320, 300, isbf, bh, bl);
            } else {
                #pragma unroll
                for (int j = 0; j < 16; ++j) {
                    int kk = k + j; float x = 0.f;
                    if (kk < 300) x = ldf(Wf1, n * 300 + kk, isbf);
                    else if (kk >= 320 && kk < 620) x = ldf(Wf2, n * 300 + (kk - 320), isbf);
                    unsigned short hh, ll; split2(x, &hh, &ll);
                    bh[j] = hh; bl[j] = ll;
                }
            }
        }
        __syncthreads();
        MM_COMPUTE()
    }
    const int n_g = n0 + w * 16 + (l & 15);
    if (n_g < 300) {
        float bb = ldf(bfv, n_g, isbf);
        #pragma unroll
        for (int r = 0; r < 4; ++r) {
            int m_g = m0 + (l >> 4) * 4 + r;
            float gp = acc[r] + bb;
            float gate = 1.0f / (1.0f + __expf(-gp));
            float rv = ws[OFF_REP  + m_g * 300 + n_g];
            float av = ws[OFF_ATTN + m_g * 300 + n_g];
            float res = (gate * rv + (1.0f - gate) * av) * (float)mask[m_g];
            if (isbf) ((__hip_bfloat16*)outv)[m_g * 300 + n_g] = __float2bfloat16(res);
            else      ((float*)outv)[m_g * 300 + n_g] = res;
        }
    }
}

extern "C" void kernel_launch(void* const* d_in, const int* in_sizes, int n_in,
                              void* d_out, int out_size, void* d_ws, size_t ws_size,
                              hipStream_t stream) {
    const void* X   = d_in[0];
    const int*  msk = (const int*)d_in[1];
    const void* Wfc = d_in[2];
    const void* bfc = d_in[3];
    const void* W1  = d_in[4];
    const void* W2  = d_in[5];
    const void* b1  = d_in[6];
    const void* Wf1 = d_in[7];
    const void* Wf2 = d_in[8];
    const void* bfv = d_in[9];
    float* ws = (float*)d_ws;

    hipLaunchKernelGGL(k_mm1,  dim3(320), dim3(256), 0, stream, X, Wfc, bfc, ws);
    hipLaunchKernelGGL(k_mm2,  dim3(640), dim3(256), 0, stream, W1, W2, b1, ws);
    hipLaunchKernelGGL(k_attn, dim3(512), dim3(320), 0, stream,
                       ws, msk, ws + OFF_ATTN);
    hipLaunchKernelGGL(k_mm3,  dim3(320), dim3(256), 0, stream,
                       Wf1, Wf2, bfv, msk, ws, d_out);
}

// Round 10
// 154.543 us; speedup vs baseline: 1.0101x; 1.0101x over previous
//
#include <hip/hip_runtime.h>
#include <hip/hip_bf16.h>

#define Dx 300
#define Mx 1024

// float-offsets into ws
#define OFF_REP    0
#define OFF_DEP    307200
#define OFF_HEAD   614400
#define OFF_ATTN   921600

typedef __attribute__((ext_vector_type(8))) short short8;
typedef __attribute__((ext_vector_type(4))) float f32x4;

union S8 { unsigned int u[4]; unsigned short s[8]; short8 v; };

__device__ __forceinline__ float bf2f(unsigned short u) {
    union { unsigned int i; float f; } v; v.i = ((unsigned int)u) << 16; return v.f;
}
__device__ __forceinline__ int detect_bf16(const void* w) {
    const unsigned short* u = (const unsigned short*)w;
    int ok = 1;
    #pragma unroll
    for (int t = 0; t < 64; ++t) { float v = bf2f(u[t]); ok &= (fabsf(v) < 1.0f) ? 1 : 0; }
    return ok;
}
__device__ __forceinline__ float ldf(const void* p, int idx, int isbf) {
    return isbf ? bf2f(((const unsigned short*)p)[idx]) : ((const float*)p)[idx];
}

// ---- register-level fragment loaders (no LDS, no barriers) ----------------

// 8 consecutive fp32 from rowp[kb..kb+8) with bounds, else 0
__device__ __forceinline__ void load8f(const float* rowp, int kb, int kmax,
                                       int valid, float* x) {
    if (valid && kb + 8 <= kmax) {
        float4 a = *(const float4*)(rowp + kb);
        float4 b = *(const float4*)(rowp + kb + 4);
        x[0]=a.x; x[1]=a.y; x[2]=a.z; x[3]=a.w;
        x[4]=b.x; x[5]=b.y; x[6]=b.z; x[7]=b.w;
    } else {
        #pragma unroll
        for (int j = 0; j < 8; ++j) {
            int k = kb + j;
            x[j] = (valid && k < kmax) ? rowp[k] : 0.f;
        }
    }
}

// truncation hi/lo split of 8 fp32 into two bf16x8 fragments (~4 VALU/elem)
__device__ __forceinline__ void split8(const float* x, short8* hv, short8* lv) {
    S8 H, L;
    #pragma unroll
    for (int p = 0; p < 4; ++p) {
        union { float f; unsigned int i; } a, b; a.f = x[2*p]; b.f = x[2*p+1];
        unsigned int ha = a.i & 0xFFFF0000u, hb = b.i & 0xFFFF0000u;
        union { unsigned int i; float f; } fa, fb; fa.i = ha; fb.i = hb;
        union { float f; unsigned int i; } la, lb;
        la.f = x[2*p] - fa.f; lb.f = x[2*p+1] - fb.f;
        H.u[p] = (ha >> 16) | hb;
        L.u[p] = (la.i >> 16) | (lb.i & 0xFFFF0000u);
    }
    *hv = H.v; *lv = L.v;
}

// 8 consecutive bf16 from rowp with bounds, else 0
__device__ __forceinline__ short8 load8bf(const unsigned short* rowp, int kb,
                                          int kmax, int valid) {
    S8 R;
    if (valid && kb + 8 <= kmax) {
        ushort4 a = *(const ushort4*)(rowp + kb);
        ushort4 b = *(const ushort4*)(rowp + kb + 4);
        R.s[0]=a.x; R.s[1]=a.y; R.s[2]=a.z; R.s[3]=a.w;
        R.s[4]=b.x; R.s[5]=b.y; R.s[6]=b.z; R.s[7]=b.w;
    } else {
        #pragma unroll
        for (int j = 0; j < 8; ++j) {
            int k = kb + j;
            R.s[j] = (valid && k < kmax) ? rowp[k] : (unsigned short)0;
        }
    }
    return R.v;
}

__device__ __forceinline__ short8 zero8() {
    S8 z; z.u[0]=0; z.u[1]=0; z.u[2]=0; z.u[3]=0; return z.v;
}

// ---------------------------------------------------------------------------
// k_mm1: rep = elu(X @ Wfc^T + bfc). grid 320 = 64mt x 5nt, 256 thr (4 waves).
// Wave w owns 16x16 tile (m0, nt*64+w*16). Barrier-free K-loop.
// ---------------------------------------------------------------------------
__global__ __launch_bounds__(256) void k_mm1(
        const void* __restrict__ Xv, const void* __restrict__ Wfc,
        const void* __restrict__ bfc, float* __restrict__ ws) {
    __shared__ int s_isbf;
    if (threadIdx.x == 0) s_isbf = detect_bf16(Wfc);
    __syncthreads();
    const int isbf = s_isbf;
    const int tid = threadIdx.x, w = tid >> 6, l = tid & 63;
    const int mt = blockIdx.x / 5, nt = blockIdx.x % 5;
    const int m0 = mt * 16;
    const int mrow = m0 + (l & 15);
    const int nrow = nt * 64 + w * 16 + (l & 15);
    const int koff = (l >> 4) * 8;
    const int bvalid = nrow < 300;
    const int nclamp = bvalid ? nrow : 0;
    f32x4 acc = {0.f, 0.f, 0.f, 0.f};
    if (isbf) {
        const unsigned short* Xp = (const unsigned short*)Xv + mrow * 300;
        const unsigned short* Wp = (const unsigned short*)Wfc + nclamp * 300;
        #pragma unroll 2
        for (int ks = 0; ks < 10; ++ks) {
            const int kb = ks * 32 + koff;
            short8 a = load8bf(Xp, kb, 300, 1);
            short8 b = load8bf(Wp, kb, 300, bvalid);
            acc = __builtin_amdgcn_mfma_f32_16x16x32_bf16(a, b, acc, 0, 0, 0);
        }
    } else {
        const float* Xp = (const float*)Xv + mrow * 300;
        const float* Wp = (const float*)Wfc + nclamp * 300;
        #pragma unroll 2
        for (int ks = 0; ks < 10; ++ks) {
            const int kb = ks * 32 + koff;
            float xa[8], xb[8];
            load8f(Xp, kb, 300, 1, xa);
            load8f(Wp, kb, 300, bvalid, xb);
            short8 ah, al, bh, bl;
            split8(xa, &ah, &al);
            split8(xb, &bh, &bl);
            acc = __builtin_amdgcn_mfma_f32_16x16x32_bf16(ah, bh, acc, 0, 0, 0);
            acc = __builtin_amdgcn_mfma_f32_16x16x32_bf16(ah, bl, acc, 0, 0, 0);
            acc = __builtin_amdgcn_mfma_f32_16x16x32_bf16(al, bh, acc, 0, 0, 0);
        }
    }
    if (bvalid) {
        float bb = ldf(bfc, nrow, isbf);
        #pragma unroll
        for (int r = 0; r < 4; ++r) {
            int m_g = m0 + (l >> 4) * 4 + r;
            float v = acc[r] + bb;
            v = v > 0.f ? v : (__expf(v) - 1.f);
            ws[OFF_REP + m_g * 300 + nrow] = v;
        }
    }
}

// ---------------------------------------------------------------------------
// k_mm2: dep = rep@W1^T + b1 ; head = rep@W2^T. grid 640 = 64mt x 10nt.
// N padded to 640: n<300 -> W1, 320<=n<620 -> W2 row n-320.
// ---------------------------------------------------------------------------
__global__ __launch_bounds__(256) void k_mm2(
        const void* __restrict__ W1, const void* __restrict__ W2,
        const void* __restrict__ b1, float* __restrict__ ws) {
    __shared__ int s_isbf;
    if (threadIdx.x == 0) s_isbf = detect_bf16(W1);
    __syncthreads();
    const int isbf = s_isbf;
    const int tid = threadIdx.x, w = tid >> 6, l = tid & 63;
    const int mt = blockIdx.x / 10, nt = blockIdx.x % 10;
    const int m0 = mt * 16;
    const int mrow = m0 + (l & 15);
    const int nrow = nt * 64 + w * 16 + (l & 15);
    const int koff = (l >> 4) * 8;
    int bvalid = 1, wrow = 0;
    const void* Wsrc = W1;
    if (nrow < 300) { wrow = nrow; Wsrc = W1; }
    else if (nrow >= 320 && nrow < 620) { wrow = nrow - 320; Wsrc = W2; }
    else bvalid = 0;
    const float* Ap = ws + OFF_REP + mrow * 300;
    f32x4 acc = {0.f, 0.f, 0.f, 0.f};
    if (isbf) {
        const unsigned short* Wp = (const unsigned short*)Wsrc + wrow * 300;
        #pragma unroll 2
        for (int ks = 0; ks < 10; ++ks) {
            const int kb = ks * 32 + koff;
            float xa[8];
            load8f(Ap, kb, 300, 1, xa);
            short8 ah, al;
            split8(xa, &ah, &al);
            short8 b = load8bf(Wp, kb, 300, bvalid);
            acc = __builtin_amdgcn_mfma_f32_16x16x32_bf16(ah, b, acc, 0, 0, 0);
            acc = __builtin_amdgcn_mfma_f32_16x16x32_bf16(al, b, acc, 0, 0, 0);
        }
    } else {
        const float* Wp = (const float*)Wsrc + wrow * 300;
        #pragma unroll 2
        for (int ks = 0; ks < 10; ++ks) {
            const int kb = ks * 32 + koff;
            float xa[8], xb[8];
            load8f(Ap, kb, 300, 1, xa);
            load8f(Wp, kb, 300, bvalid, xb);
            short8 ah, al, bh, bl;
            split8(xa, &ah, &al);
            split8(xb, &bh, &bl);
            acc = __builtin_amdgcn_mfma_f32_16x16x32_bf16(ah, bh, acc, 0, 0, 0);
            acc = __builtin_amdgcn_mfma_f32_16x16x32_bf16(ah, bl, acc, 0, 0, 0);
            acc = __builtin_amdgcn_mfma_f32_16x16x32_bf16(al, bh, acc, 0, 0, 0);
        }
    }
    if (nrow < 300) {
        float bb = ldf(b1, nrow, isbf);
        #pragma unroll
        for (int r = 0; r < 4; ++r) {
            int m_g = m0 + (l >> 4) * 4 + r;
            ws[OFF_DEP + m_g * 300 + nrow] = acc[r] + bb;
        }
    } else if (nrow >= 320 && nrow < 620) {
        #pragma unroll
        for (int r = 0; r < 4; ++r) {
            int m_g = m0 + (l >> 4) * 4 + r;
            ws[OFF_HEAD + m_g * 300 + (nrow - 320)] = acc[r];
        }
    }
}

// ---------------------------------------------------------------------------
// k_attn: single-pass branchless, fixed shift m=C (round-4 proven).
// ---------------------------------------------------------------------------
__global__ __launch_bounds__(320) void k_attn(
        const float* __restrict__ ws_ro, const int* __restrict__ mask,
        float* __restrict__ attn) {
    const float* dep  = ws_ro + OFF_DEP;
    const float* head = ws_ro + OFF_HEAD;
    const float* rep  = ws_ro + OFF_REP;
    __shared__ float mkf[256];
    const int blk = blockIdx.x;
    const int b = blk >> 7;
    const int tile = blk & 127;
    const int u = tile >> 1;
    const int i0 = (tile & 1) ? (254 - 2 * u) : (2 * u);
    const int tid = threadIdx.x;
    if (tid < 256) mkf[tid] = (float)mask[b * 256 + tid];
    __syncthreads();
    const int d = tid;
    if (d >= Dx) return;
    const int base = b * 256;

    const float hv0 = head[(base + i0) * Dx + d];
    const float hv1 = head[(base + i0 + 1) * Dx + d];
    const float pw0 = __expf(0.4f * hv0);
    const float pw1 = __expf(0.4f * hv1);

    float s0 = 0.f, r0 = 0.f, s1 = 0.f, r1 = 0.f;
    {
        const int j = i0 + 1;
        float dv = dep[(base + j) * Dx + d];
        float rv = rep[(base + j) * Dx + d];
        float mk = mkf[j];
        float ex = __expf(0.4f * dv);
        float u0 = fmaf(ex, pw0, 1.0f);
        float e0 = __expf(-10.0f * __builtin_amdgcn_rcpf(u0));
        float em0 = e0 * mk;
        s0 += em0; r0 = fmaf(em0, rv, r0);
    }
    const float* dp = dep + base * Dx + d;
    const float* rp = rep + base * Dx + d;
    #pragma unroll 4
    for (int j = i0 + 2; j < 256; ++j) {
        float dv = dp[j * Dx];
        float rv = rp[j * Dx];
        float mk = mkf[j];
        float ex = __expf(0.4f * dv);
        float u0 = fmaf(ex, pw0, 1.0f);
        float u1 = fmaf(ex, pw1, 1.0f);
        float e0 = __expf(-10.0f * __builtin_amdgcn_rcpf(u0));
        float e1 = __expf(-10.0f * __builtin_amdgcn_rcpf(u1));
        float em0 = e0 * mk;
        float em1 = e1 * mk;
        s0 += em0; r0 = fmaf(em0, rv, r0);
        s1 += em1; r1 = fmaf(em1, rv, r1);
    }
    const float den0 = s0 + (s0 == 0.f ? 1.f : 0.f) + 1e-20f;
    const float den1 = s1 + (s1 == 0.f ? 1.f : 0.f) + 1e-20f;
    attn[(base + i0) * Dx + d]     = r0 / den0;
    attn[(base + i0 + 1) * Dx + d] = r1 / den1;
}

// ---------------------------------------------------------------------------
// k_mm3: gate GEMM, A=[rep(0:300)|0|attn(320:620)|0] Kpad=640, B=[Wf1|Wf2];
// sigmoid blend, mask, store. grid 320 = 64mt x 5nt.
// ---------------------------------------------------------------------------
__global__ __launch_bounds__(256) void k_mm3(
        const void* __restrict__ Wf1, const void* __restrict__ Wf2,
        const void* __restrict__ bfv, const int* __restrict__ mask,
        float* __restrict__ ws, void* __restrict__ outv) {
    __shared__ int s_isbf;
    if (threadIdx.x == 0) s_isbf = detect_bf16(Wf1);
    __syncthreads();
    const int isbf = s_isbf;
    const int tid = threadIdx.x, w = tid >> 6, l = tid & 63;
    const int mt = blockIdx.x / 5, nt = blockIdx.x % 5;
    const int m0 = mt * 16;
    const int mrow = m0 + (l & 15);
    const int nrow = nt * 64 + w * 16 + (l & 15);
    const int koff = (l >> 4) * 8;
    const int bvalid = nrow < 300;
    const int nclamp = bvalid ? nrow : 0;
    const float* repp = ws + OFF_REP  + mrow * 300;
    const float* attp = ws + OFF_ATTN + mrow * 300;
    f32x4 acc = {0.f, 0.f, 0.f, 0.f};
    #pragma unroll 2
    for (int ks = 0; ks < 20; ++ks) {
        const int kb = ks * 32 + koff;
        // A fragment from two-region layout
        const float* asrc; int akk, av = 1;
        if (kb < 300) { asrc = repp; akk = kb; }
        else if (kb >= 320 && kb < 620) { asrc = attp; akk = kb - 320; }
        else { asrc = repp; akk = 0; av = 0; }
        float xa[8];
        load8f(asrc, akk, 300, av, xa);
        short8 ah, al;
        split8(xa, &ah, &al);
        // B fragment: Wf1 for k<300, Wf2 for 320<=k<620
        short8 bh, bl;
        int bkk, bv = bvalid;
        const void* bsrc;
        if (kb < 300) { bsrc = Wf1; bkk = kb; }
        else if (kb >= 320 && kb < 620) { bsrc = Wf2; bkk = kb - 320; }
        else { bsrc = Wf1; bkk = 0; bv = 0; }
        if (isbf) {
            bh = load8bf((const unsigned short*)bsrc + nclamp * 300, bkk, 300, bv);
            bl = zero8();
            acc = __builtin_amdgcn_mfma_f32_16x16x32_bf16(ah, bh, acc, 0, 0, 0);
            acc = __builtin_amdgcn_mfma_f32_16x16x32_bf16(al, bh, acc, 0, 0, 0);
        } else {
            float xb[8];
            load8f((const float*)bsrc + nclamp * 300, bkk, 300, bv, xb);
            split8(xb, &bh, &bl);
            acc = __builtin_amdgcn_mfma_f32_16x16x32_bf16(ah, bh, acc, 0, 0, 0);
            acc = __builtin_amdgcn_mfma_f32_16x16x32_bf16(ah, bl, acc, 0, 0, 0);
            acc = __builtin_amdgcn_mfma_f32_16x16x32_bf16(al, bh, acc, 0, 0, 0);
        }
    }
    if (bvalid) {
        float bb = ldf(bfv, nrow, isbf);
        #pragma unroll
        for (int r = 0; r < 4; ++r) {
            int m_g = m0 + (l >> 4) * 4 + r;
            float gp = acc[r] + bb;
            float gate = 1.0f / (1.0f + __expf(-gp));
            float rv = ws[OFF_REP  + m_g * 300 + nrow];
            float av = ws[OFF_ATTN + m_g * 300 + nrow];
            float res = (gate * rv + (1.0f - gate) * av) * (float)mask[m_g];
            if (isbf) ((__hip_bfloat16*)outv)[m_g * 300 + nrow] = __float2bfloat16(res);
            else      ((float*)outv)[m_g * 300 + nrow] = res;
        }
    }
}

extern "C" void kernel_launch(void* const* d_in, const int* in_sizes, int n_in,
                              void* d_out, int out_size, void* d_ws, size_t ws_size,
                              hipStream_t stream) {
    const void* X   = d_in[0];
    const int*  msk = (const int*)d_in[1];
    const void* Wfc = d_in[2];
    const void* bfc = d_in[3];
    const void* W1  = d_in[4];
    const void* W2  = d_in[5];
    const void* b1  = d_in[6];
    const void* Wf1 = d_in[7];
    const void* Wf2 = d_in[8];
    const void* bfv = d_in[9];
    float* ws = (float*)d_ws;

    hipLaunchKernelGGL(k_mm1,  dim3(320), dim3(256), 0, stream, X, Wfc, bfc, ws);
    hipLaunchKernelGGL(k_mm2,  dim3(640), dim3(256), 0, stream, W1, W2, b1, ws);
    hipLaunchKernelGGL(k_attn, dim3(512), dim3(320), 0, stream,
                       ws, msk, ws + OFF_ATTN);
    hipLaunchKernelGGL(k_mm3,  dim3(320), dim3(256), 0, stream,
                       Wf1, Wf2, bfv, msk, ws, d_out);
}